// Round 8
// baseline (467.906 us; speedup 1.0000x reference)
//
#include <hip/hip_runtime.h>

#define S7 7
#define NCELL 49            // S*S
#define CH 30
#define IMG_F (CH * NCELL)  // 1470 floats per image
#define K_IMG 2             // images per block; LDS = 2*1470*2*4B = 23.5 KB -> 6 blocks/CU
#define BLK 256
#define NF4 (K_IMG * IMG_F / 4)  // 735 float4 per tensor per block

typedef __attribute__((address_space(1))) const void global_cvoid;
typedef __attribute__((address_space(3))) void lds_void;

__global__ __launch_bounds__(BLK) void yolo_loss_fused(
    const float4* __restrict__ pred4,
    const float4* __restrict__ lab4,
    float* __restrict__ partials,
    unsigned int* __restrict__ counter,
    float* __restrict__ out,
    float inv_B)
{
    __shared__ float4 sp4[NF4];
    __shared__ float4 sl4[NF4];
    const float* sp = (const float*)sp4;
    const float* sl = (const float*)sl4;

    const int tid = threadIdx.x;

    // ---- stage: async global->LDS, 16B/lane, linear dest (grid is exact: no guard) ----
    const size_t g4base = (size_t)blockIdx.x * NF4;
    for (int i = tid; i < NF4; i += BLK) {
        __builtin_amdgcn_global_load_lds(
            (global_cvoid*)(pred4 + g4base + i),
            (lds_void*)(&sp4[i]), 16, 0, 0);
        __builtin_amdgcn_global_load_lds(
            (global_cvoid*)(lab4 + g4base + i),
            (lds_void*)(&sl4[i]), 16, 0, 0);
    }
    __syncthreads();   // drains vmcnt; LDS tile ready

    // ---- compute: one thread per cell (98 of 256), from LDS ----
    float contrib = 0.0f;
    if (tid < K_IMG * NCELL) {
        const int img  = tid / NCELL;
        const int cell = tid - img * NCELL;
        const float* __restrict__ pb = sp + img * IMG_F + cell;
        const float* __restrict__ lb = sl + img * IMG_F + cell;

        float p[10], l[10];
        #pragma unroll
        for (int c = 0; c < 10; ++c) {
            p[c] = pb[c * NCELL];
            l[c] = lb[c * NCELL];
        }
        float cls = 0.0f;
        #pragma unroll
        for (int c = 10; c < CH; ++c) {
            float d = pb[c * NCELL] - lb[c * NCELL];
            cls += d * d;
        }

        const int   row = cell / S7;
        const float mi = (float)row;
        const float nj = (float)(cell - row * S7);
        const float invS = 1.0f / 7.0f;

        float ax1, ay1, ax2, ay2;
        {
            float cx = (p[0] + mi) * invS, cy = (p[1] + nj) * invS;
            ax1 = cx - 0.5f * p[2]; ay1 = cy - 0.5f * p[3];
            ax2 = cx + 0.5f * p[2]; ay2 = cy + 0.5f * p[3];
        }
        float bx1, by1, bx2, by2;
        {
            float cx = (p[5] + mi) * invS, cy = (p[6] + nj) * invS;
            bx1 = cx - 0.5f * p[7]; by1 = cy - 0.5f * p[8];
            bx2 = cx + 0.5f * p[7]; by2 = cy + 0.5f * p[8];
        }
        float gx1, gy1, gx2, gy2;
        {
            float cx = (l[0] + mi) * invS, cy = (l[1] + nj) * invS;
            gx1 = cx - 0.5f * l[2]; gy1 = cy - 0.5f * l[3];
            gx2 = cx + 0.5f * l[2]; gy2 = cy + 0.5f * l[3];
        }

        float iou1, iou2;
        {
            float ix1 = fmaxf(ax1, gx1), iy1 = fmaxf(ay1, gy1);
            float ix2 = fminf(ax2, gx2), iy2 = fminf(ay2, gy2);
            float inter = fmaxf(ix2 - ix1, 0.0f) * fmaxf(iy2 - iy1, 0.0f);
            float a1 = (ax2 - ax1) * (ay2 - ay1);
            float a2 = (gx2 - gx1) * (gy2 - gy1);
            float denom = a1 + a2 - inter;
            iou1 = (inter > 0.0f) ? inter / denom : 0.0f;
        }
        {
            float ix1 = fmaxf(bx1, gx1), iy1 = fmaxf(by1, gy1);
            float ix2 = fminf(bx2, gx2), iy2 = fminf(by2, gy2);
            float inter = fmaxf(ix2 - ix1, 0.0f) * fmaxf(iy2 - iy1, 0.0f);
            float a1 = (bx2 - bx1) * (by2 - by1);
            float a2 = (gx2 - gx1) * (gy2 - gy1);
            float denom = a1 + a2 - inter;
            iou2 = (inter > 0.0f) ? inter / denom : 0.0f;
        }

        const bool resp1 = (iou1 >= iou2);

        float d0 = p[0] - l[0], d1 = p[1] - l[1];
        float s2 = __builtin_sqrtf(p[2]) - __builtin_sqrtf(l[2]);
        float s3 = __builtin_sqrtf(p[3]) - __builtin_sqrtf(l[3]);
        float coor1 = 5.0f * (d0 * d0 + d1 * d1 + s2 * s2 + s3 * s3);

        float e0 = p[5] - l[5], e1 = p[6] - l[6];
        float t2 = __builtin_sqrtf(p[7]) - __builtin_sqrtf(l[7]);
        float t3 = __builtin_sqrtf(p[8]) - __builtin_sqrtf(l[8]);
        float coor2 = 5.0f * (e0 * e0 + e1 * e1 + t2 * t2 + t3 * t3);

        float o1 = p[4] - iou1; o1 *= o1;
        float o2 = p[9] - iou2; o2 *= o2;

        float coor       = resp1 ? coor1 : coor2;
        float obj_conf   = resp1 ? o1 : o2;
        float noobj_resp = 0.5f * (resp1 ? o2 : o1);
        float noobj_cell = 0.5f * (p[4] * p[4] + p[9] * p[9]);

        const bool obj = (l[4] == 1.0f);
        contrib = obj ? (coor + obj_conf + noobj_resp + cls) : noobj_cell;
    }

    // ---- block reduction: wave shuffle -> LDS -> one partial per block ----
    #pragma unroll
    for (int off = 32; off > 0; off >>= 1)
        contrib += __shfl_down(contrib, off, 64);

    __shared__ float wsum[BLK / 64];
    __shared__ bool amLast;
    const int lane = tid & 63;
    const int wid  = tid >> 6;
    if (lane == 0) wsum[wid] = contrib;
    __syncthreads();

    if (tid == 0) {
        float bs = wsum[0] + wsum[1] + wsum[2] + wsum[3];
        // device-scope store so other XCDs' last block sees it
        __hip_atomic_store(&partials[blockIdx.x], bs,
                           __ATOMIC_RELAXED, __HIP_MEMORY_SCOPE_AGENT);
        __threadfence();   // release: partial visible before counter bump
        unsigned old = __hip_atomic_fetch_add(counter, 1u,
                           __ATOMIC_ACQ_REL, __HIP_MEMORY_SCOPE_AGENT);
        amLast = (old == gridDim.x - 1);
    }
    __syncthreads();       // broadcast amLast (uniform across block)

    if (amLast) {
        __threadfence();   // acquire side
        float s = 0.0f;
        for (int i = tid; i < (int)gridDim.x; i += BLK)
            s += __hip_atomic_load(&partials[i],
                                   __ATOMIC_RELAXED, __HIP_MEMORY_SCOPE_AGENT);

        #pragma unroll
        for (int off = 32; off > 0; off >>= 1)
            s += __shfl_down(s, off, 64);

        if (lane == 0) wsum[wid] = s;
        __syncthreads();   // uniform branch -> barrier is safe
        if (tid == 0)
            out[0] = (wsum[0] + wsum[1] + wsum[2] + wsum[3]) * inv_B;
    }
}

extern "C" void kernel_launch(void* const* d_in, const int* in_sizes, int n_in,
                              void* d_out, int out_size, void* d_ws, size_t ws_size,
                              hipStream_t stream) {
    const float4* pred4 = (const float4*)d_in[0];
    const float4* lab4  = (const float4*)d_in[1];
    float* out = (float*)d_out;

    const int B = in_sizes[0] / IMG_F;     // 16384
    const int grid = B / K_IMG;            // 8192 blocks (exact)

    float* partials = (float*)d_ws;
    unsigned int* counter = (unsigned int*)((char*)d_ws + (size_t)grid * sizeof(float));

    // zero the completion counter each call (graph-capture-safe, deterministic)
    hipMemsetAsync(counter, 0, sizeof(unsigned int), stream);

    yolo_loss_fused<<<grid, BLK, 0, stream>>>(pred4, lab4, partials, counter, out,
                                              1.0f / (float)B);
}

// Round 9
// 36.737 us; speedup vs baseline: 12.7366x; 12.7366x over previous
//
#include <hip/hip_runtime.h>

#define S7 7
#define NCELL 49            // S*S
#define CH 30
#define IMG_F (CH * NCELL)  // 1470 floats per image
#define K_IMG 2             // images per block; LDS = 2*1470*2*4B = 23.5 KB -> 6 blocks/CU
#define BLK 256
#define NF4 (K_IMG * IMG_F / 4)  // 735 float4 per tensor per block

typedef __attribute__((address_space(1))) const void global_cvoid;
typedef __attribute__((address_space(3))) void lds_void;

__global__ __launch_bounds__(BLK) void yolo_loss_stage1(
    const float4* __restrict__ pred4,
    const float4* __restrict__ lab4,
    float* __restrict__ partials,
    int B)
{
    __shared__ float4 sp4[NF4];
    __shared__ float4 sl4[NF4];
    const float* sp = (const float*)sp4;
    const float* sl = (const float*)sl4;

    // ---- stage: async global->LDS, 16B per lane per instruction ----
    const size_t g4base = (size_t)blockIdx.x * NF4;
    const size_t total4 = ((size_t)B * IMG_F) / 4;
    for (int i = threadIdx.x; i < NF4; i += BLK) {
        if (g4base + i < total4) {
            __builtin_amdgcn_global_load_lds(
                (global_cvoid*)(pred4 + g4base + i),
                (lds_void*)(&sp4[i]), 16, 0, 0);
            __builtin_amdgcn_global_load_lds(
                (global_cvoid*)(lab4 + g4base + i),
                (lds_void*)(&sl4[i]), 16, 0, 0);
        }
    }
    __syncthreads();   // compiler emits vmcnt(0) drain before s_barrier

    // ---- compute: one thread per cell (98 of 256 threads), reads from LDS ----
    const int b0 = blockIdx.x * K_IMG;
    const int nimg = (B - b0 < K_IMG) ? (B - b0) : K_IMG;

    float contrib = 0.0f;
    const int tid = threadIdx.x;
    if (tid < nimg * NCELL) {
        const int img  = tid / NCELL;
        const int cell = tid - img * NCELL;
        const float* __restrict__ pb = sp + img * IMG_F + cell;
        const float* __restrict__ lb = sl + img * IMG_F + cell;

        float p[10], l[10];
        #pragma unroll
        for (int c = 0; c < 10; ++c) {
            p[c] = pb[c * NCELL];
            l[c] = lb[c * NCELL];
        }
        float cls = 0.0f;
        #pragma unroll
        for (int c = 10; c < CH; ++c) {
            float d = pb[c * NCELL] - lb[c * NCELL];
            cls += d * d;
        }

        const int   row = cell / S7;
        const float mi = (float)row;
        const float nj = (float)(cell - row * S7);
        const float invS = 1.0f / 7.0f;

        float ax1, ay1, ax2, ay2;
        {
            float cx = (p[0] + mi) * invS, cy = (p[1] + nj) * invS;
            ax1 = cx - 0.5f * p[2]; ay1 = cy - 0.5f * p[3];
            ax2 = cx + 0.5f * p[2]; ay2 = cy + 0.5f * p[3];
        }
        float bx1, by1, bx2, by2;
        {
            float cx = (p[5] + mi) * invS, cy = (p[6] + nj) * invS;
            bx1 = cx - 0.5f * p[7]; by1 = cy - 0.5f * p[8];
            bx2 = cx + 0.5f * p[7]; by2 = cy + 0.5f * p[8];
        }
        float gx1, gy1, gx2, gy2;
        {
            float cx = (l[0] + mi) * invS, cy = (l[1] + nj) * invS;
            gx1 = cx - 0.5f * l[2]; gy1 = cy - 0.5f * l[3];
            gx2 = cx + 0.5f * l[2]; gy2 = cy + 0.5f * l[3];
        }

        float iou1, iou2;
        {
            float ix1 = fmaxf(ax1, gx1), iy1 = fmaxf(ay1, gy1);
            float ix2 = fminf(ax2, gx2), iy2 = fminf(ay2, gy2);
            float inter = fmaxf(ix2 - ix1, 0.0f) * fmaxf(iy2 - iy1, 0.0f);
            float a1 = (ax2 - ax1) * (ay2 - ay1);
            float a2 = (gx2 - gx1) * (gy2 - gy1);
            float denom = a1 + a2 - inter;
            iou1 = (inter > 0.0f) ? inter / denom : 0.0f;
        }
        {
            float ix1 = fmaxf(bx1, gx1), iy1 = fmaxf(by1, gy1);
            float ix2 = fminf(bx2, gx2), iy2 = fminf(by2, gy2);
            float inter = fmaxf(ix2 - ix1, 0.0f) * fmaxf(iy2 - iy1, 0.0f);
            float a1 = (bx2 - bx1) * (by2 - by1);
            float a2 = (gx2 - gx1) * (gy2 - gy1);
            float denom = a1 + a2 - inter;
            iou2 = (inter > 0.0f) ? inter / denom : 0.0f;
        }

        const bool resp1 = (iou1 >= iou2);

        float d0 = p[0] - l[0], d1 = p[1] - l[1];
        float s2 = __builtin_sqrtf(p[2]) - __builtin_sqrtf(l[2]);
        float s3 = __builtin_sqrtf(p[3]) - __builtin_sqrtf(l[3]);
        float coor1 = 5.0f * (d0 * d0 + d1 * d1 + s2 * s2 + s3 * s3);

        float e0 = p[5] - l[5], e1 = p[6] - l[6];
        float t2 = __builtin_sqrtf(p[7]) - __builtin_sqrtf(l[7]);
        float t3 = __builtin_sqrtf(p[8]) - __builtin_sqrtf(l[8]);
        float coor2 = 5.0f * (e0 * e0 + e1 * e1 + t2 * t2 + t3 * t3);

        float o1 = p[4] - iou1; o1 *= o1;
        float o2 = p[9] - iou2; o2 *= o2;

        float coor       = resp1 ? coor1 : coor2;
        float obj_conf   = resp1 ? o1 : o2;
        float noobj_resp = 0.5f * (resp1 ? o2 : o1);
        float noobj_cell = 0.5f * (p[4] * p[4] + p[9] * p[9]);

        const bool obj = (l[4] == 1.0f);
        contrib = obj ? (coor + obj_conf + noobj_resp + cls) : noobj_cell;
    }

    // ---- block reduction: wave shuffle -> LDS -> one partial store (no atomics) ----
    #pragma unroll
    for (int off = 32; off > 0; off >>= 1)
        contrib += __shfl_down(contrib, off, 64);

    __shared__ float wsum[BLK / 64];
    const int lane = threadIdx.x & 63;
    const int wid  = threadIdx.x >> 6;
    if (lane == 0) wsum[wid] = contrib;
    __syncthreads();
    if (threadIdx.x == 0)
        partials[blockIdx.x] = wsum[0] + wsum[1] + wsum[2] + wsum[3];
}

__global__ __launch_bounds__(1024) void yolo_loss_stage2(
    const float* __restrict__ partials,
    float* __restrict__ out,
    int nparts, float inv_B)
{
    float s = 0.0f;
    for (int i = threadIdx.x; i < nparts; i += 1024)
        s += partials[i];

    #pragma unroll
    for (int off = 32; off > 0; off >>= 1)
        s += __shfl_down(s, off, 64);

    __shared__ float wsum[16];
    const int lane = threadIdx.x & 63;
    const int wid  = threadIdx.x >> 6;
    if (lane == 0) wsum[wid] = s;
    __syncthreads();
    if (threadIdx.x == 0) {
        float bs = 0.0f;
        #pragma unroll
        for (int w = 0; w < 16; ++w) bs += wsum[w];
        out[0] = bs * inv_B;
    }
}

extern "C" void kernel_launch(void* const* d_in, const int* in_sizes, int n_in,
                              void* d_out, int out_size, void* d_ws, size_t ws_size,
                              hipStream_t stream) {
    const float4* pred4 = (const float4*)d_in[0];
    const float4* lab4  = (const float4*)d_in[1];
    float* out = (float*)d_out;
    float* partials = (float*)d_ws;

    const int B = in_sizes[0] / IMG_F;                // 16384
    const int grid = (B + K_IMG - 1) / K_IMG;         // 8192 blocks

    yolo_loss_stage1<<<grid, BLK, 0, stream>>>(pred4, lab4, partials, B);
    yolo_loss_stage2<<<1, 1024, 0, stream>>>(partials, out, grid, 1.0f / (float)B);
}